// Round 17
// baseline (725.427 us; speedup 1.0000x reference)
//
#include <hip/hip_runtime.h>
#include <stdint.h>

typedef _Float16 f16;
typedef _Float16 f16x8 __attribute__((ext_vector_type(8)));
typedef float    f32x4 __attribute__((ext_vector_type(4)));
typedef unsigned long long u64;

#define L_    128
#define B_    64
#define E_    512
#define H_    512
#define G3    1536   // 3*H
#define NCOL  3072   // 2*3H

__device__ __forceinline__ float sigm_(float x){ return 1.0f/(1.0f + __expf(-x)); }
__device__ __forceinline__ float tanh_(float x){ return 1.0f - 2.0f/(__expf(2.0f*x) + 1.0f); }

// ---------------- P1: embedding gather, f32 -> f16 (+ flag zeroing in block 0) ----------------
__global__ __launch_bounds__(256) void k_embed(const int* __restrict__ xs,
                                               const float* __restrict__ emb,
                                               f16* __restrict__ Xe,
                                               uint4* __restrict__ flags4){
  if (blockIdx.x == 0){
    flags4[threadIdx.x]       = make_uint4(0,0,0,0);   // 4KB
    flags4[256 + threadIdx.x] = make_uint4(0,0,0,0);   // 8KB total
  }
  int row = blockIdx.x*2 + (threadIdx.x >> 7);       // 2 rows / block
  int c   = (threadIdx.x & 127) * 4;
  int idx = xs[row];
  float4 v = *(const float4*)(emb + (size_t)idx*E_ + c);
  union { f16 h[4]; uint2 u; } p;
  p.h[0] = (f16)v.x; p.h[1] = (f16)v.y; p.h[2] = (f16)v.z; p.h[3] = (f16)v.w;
  *(uint2*)(Xe + (size_t)row*E_ + c) = p.u;
}

// ---------------- P2: transpose+cast 4 weight matrices (512x1536 f32 -> 1536x512 f16) ----------------
__global__ __launch_bounds__(256) void k_transpose(const float* __restrict__ Wx_f, const float* __restrict__ Wx_b,
                                                   const float* __restrict__ Wh_f, const float* __restrict__ Wh_b,
                                                   f16* __restrict__ WxT, f16* __restrict__ WhT){
  int mat = blockIdx.z;
  const float* src = mat==0 ? Wx_f : mat==1 ? Wx_b : mat==2 ? Wh_f : Wh_b;
  f16* dst = (mat < 2) ? (WxT + (size_t)mat*G3*E_) : (WhT + (size_t)(mat-2)*G3*H_);
  int n0 = blockIdx.x*64, k0 = blockIdx.y*64;
  __shared__ f16 tile[64][65];
  int tid = threadIdx.x;
  for (int i=0;i<16;i++){
    int r = i*4 + (tid>>6);      // k
    int c = tid & 63;            // n
    tile[r][c] = (f16)src[(size_t)(k0+r)*G3 + n0 + c];
  }
  __syncthreads();
  for (int i=0;i<16;i++){
    int n = i*4 + (tid>>6);
    int k = tid & 63;
    dst[(size_t)(n0+n)*512 + k0 + k] = tile[k][n];
  }
}

// ---------------- G: xw2[t][col][b] = (Xe @ WxT^T + bias), f16 MFMA 128x128 tiles ----------------
__global__ __launch_bounds__(256) void k_gemm(const f16* __restrict__ Xe, const f16* __restrict__ WxT,
                                              const float* __restrict__ bf, const float* __restrict__ bb,
                                              f16* __restrict__ xw2){
  __shared__ __align__(16) f16 sA[128*32];
  __shared__ __align__(16) f16 sB[128*32];
  const int tid = threadIdx.x;
  const int l = tid & 63, w = tid >> 6;
  const int wr = w >> 1, wc = w & 1;
  const int m0 = blockIdx.y*128, n0 = blockIdx.x*128;
  const int rl = l & 15, sg = l >> 4;
  f32x4 acc[4][4] = {};
  for (int kk=0; kk<16; ++kk){
    __syncthreads();
    for (int i=0;i<2;i++){
      int c = i*256 + tid; int row = c>>2, s = c&3;
      int sw = s ^ ((row>>1)&3);                       // bank-swizzle for 64B rows
      *(uint4*)&sA[row*32 + sw*8] = *(const uint4*)(Xe  + (size_t)(m0+row)*512 + kk*32 + s*8);
      *(uint4*)&sB[row*32 + sw*8] = *(const uint4*)(WxT + (size_t)(n0+row)*512 + kk*32 + s*8);
    }
    __syncthreads();
    f16x8 a[4], b[4];
    for (int mi=0;mi<4;mi++){ int m=(wr*4+mi)*16+rl; a[mi] = *(const f16x8*)&sA[m*32 + ((sg^((m>>1)&3))*8)]; }
    for (int nj=0;nj<4;nj++){ int n=(wc*4+nj)*16+rl; b[nj] = *(const f16x8*)&sB[n*32 + ((sg^((n>>1)&3))*8)]; }
    for (int mi=0;mi<4;mi++)
      for (int nj=0;nj<4;nj++)
        acc[mi][nj] = __builtin_amdgcn_mfma_f32_16x16x32_f16(a[mi], b[nj], acc[mi][nj], 0,0,0);
  }
  // epilogue: write transposed layout xw2[t][n][b] (b fastest, 64 per (t,n))
  for (int nj=0;nj<4;nj++){
    int n = n0 + (wc*4+nj)*16 + rl;
    float bias = (n < G3) ? bf[n] : bb[n-G3];
    for (int mi=0;mi<4;mi++){
      int sub = (wr*4+mi)*16 + sg*4;       // row within 128-tile
      int t   = (m0 + sub) >> 6;
      int b0  = sub & 63;
      union { f16 h[4]; uint2 u; } p;
      for (int r=0;r<4;r++) p.h[r] = (f16)(acc[mi][nj][r] + bias);
      *(uint2*)(xw2 + ((size_t)t*NCOL + n)*B_ + b0) = p.u;
    }
  }
}

// ---------------- S: bidirectional GRU scan, 8 groups x 8 producers ----------------
// grid = 64 blocks x 256 threads: dir = bx>>5, m = (bx>>3)&3 (batch tile of 16 rows),
// n = bx&7 (feature slice of 64, 4 waves x 16 features). Group (dir,m) = 8 producers
// syncing only among themselves (fan-in 16 -> 8 vs rd16); groups drift independently.
// Per wave: 48 Wh B-fragments pinned in regs (loaded once from global). Per-step:
// poll 8 flags -> 32 atomic 8B h-loads -> 48 MFMA -> gates -> per-wave 16x16 LDS
// transpose -> 8B publishes -> 4-wave barrier (drains vmcnt) -> per-block flag.
__global__ __launch_bounds__(256, 1) void k_scan(const f16* __restrict__ xw2, const f16* __restrict__ WhT,
                                                 f16* __restrict__ hbuf, const float* __restrict__ mask,
                                                 float* __restrict__ out, unsigned* __restrict__ flags){
  const int dir = blockIdx.x >> 5;
  const int m   = (blockIdx.x >> 3) & 3;
  const int n   = blockIdx.x & 7;
  const int gidx = dir*4 + m;                 // sync group (8 total)
  __shared__ __align__(16) f16 sX[4*16*16];   // 2KB: per-wave 16x16 transpose scratch
  const int tid = threadIdx.x, l = tid & 63, wv = tid >> 6;   // wv in {0..3}
  const int fl = l & 15, sg = l >> 4;
  const int fbase = n*64 + wv*16;             // this wave's 16 features (within 512)
  // one-time: 48 B-fragments (Wh cols for z,r,h of our features) direct from global, pinned
  f16x8 pz[16], pr[16], ph[16];
  {
    const f16* wb = WhT + (size_t)dir*G3*512;
    #pragma unroll
    for (int kk=0;kk<16;kk++){
      int ko = kk*32 + sg*8;
      pz[kk] = *(const f16x8*)(wb + (size_t)(       fbase + fl)*512 + ko);
      pr[kk] = *(const f16x8*)(wb + (size_t)( 512 + fbase + fl)*512 + ko);
      ph[kk] = *(const f16x8*)(wb + (size_t)(1024 + fbase + fl)*512 + ko);
    }
  }
  #pragma unroll
  for (int kk=0;kk<16;kk++){
    asm volatile("" : "+v"(pz[kk]));
    asm volatile("" : "+v"(pr[kk]));
    asm volatile("" : "+v"(ph[kk]));
  }
  float hstate[4] = {0.f,0.f,0.f,0.f};
  float* out2 = out + (size_t)L_*B_*1024;
  const int mb = m*16 + sg*4;                 // absolute batch base of this lane's C rows
  unsigned* myflag = flags + (size_t)(n*8 + gidx)*16;                  // 64B-strided
  const unsigned* pollp = flags + (size_t)((l&7)*8 + gidx)*16;         // 8 group flags
  f16* const sXw = &sX[wv*256];               // this wave's 512B transpose tile
  const int prow = l >> 2, pf = (l & 3)*4;    // publish mapping after transpose

  for (int ti=0; ti<128; ++ti){
    const int t = dir ? (127 - ti) : ti;
    // ---- prefetch xw gates + mask (independent of h; hides under poll) ----
    size_t xb = ((size_t)t*NCOL + dir*G3 + fbase + fl)*B_ + mb;
    union { uint2 u; f16 h[4]; } xzv, xrv, xhv;
    xzv.u = *(const uint2*)(xw2 + xb);
    xrv.u = *(const uint2*)(xw2 + xb + (size_t)512*B_);
    xhv.u = *(const uint2*)(xw2 + xb + (size_t)1024*B_);
    float4 mv4 = *(const float4*)(mask + t*B_ + mb);
    // ---- wait for previous step's h (this group only), then hw = h @ Wh ----
    f32x4 az = {0,0,0,0}, ar = {0,0,0,0}, ah = {0,0,0,0};
    if (ti){
      unsigned tgt = (unsigned)ti;
      while (true){
        unsigned f = __hip_atomic_load(pollp, __ATOMIC_RELAXED, __HIP_MEMORY_SCOPE_AGENT);
        if (__all((int)(f >= tgt))) break;
      }
      // group h buffer: 16 rows x 512 f16; A-row = batch-within-tile = fl; row = 128 u64
      const u64* hq = (const u64*)(hbuf + ((size_t)gidx*2 + (ti&1))*(16*512)) + (size_t)fl*128;
      u64 q[32];
      #pragma unroll
      for (int kk=0;kk<16;kk++){
        int j = kk*8 + sg*2;                // == (kk*4+sg)*2
        q[2*kk  ] = __hip_atomic_load(hq + j,     __ATOMIC_RELAXED, __HIP_MEMORY_SCOPE_AGENT);
        q[2*kk+1] = __hip_atomic_load(hq + j + 1, __ATOMIC_RELAXED, __HIP_MEMORY_SCOPE_AGENT);
      }
      #pragma unroll
      for (int kk=0;kk<16;kk++){
        union { u64 d[2]; f16x8 h; } a;
        a.d[0] = q[2*kk]; a.d[1] = q[2*kk+1];
        az = __builtin_amdgcn_mfma_f32_16x16x32_f16(a.h, pz[kk], az, 0,0,0);
        ar = __builtin_amdgcn_mfma_f32_16x16x32_f16(a.h, pr[kk], ar, 0,0,0);
        ah = __builtin_amdgcn_mfma_f32_16x16x32_f16(a.h, ph[kk], ah, 0,0,0);
      }
    }
    // ---- gates + state update (lane = feature fbase+fl, batch rows mb..mb+3) ----
    #pragma unroll
    for (int r=0;r<4;r++){
      float z  = sigm_((float)xzv.h[r] + az[r]);
      float rr = sigm_((float)xrv.h[r] + ar[r]);
      float ht = tanh_((float)xhv.h[r] + rr*ah[r]);
      float mv = (&mv4.x)[r];
      float hn = (1.0f - z)*hstate[r] + z*ht;
      hn = mv*hn + (1.0f - mv)*hstate[r];
      hstate[r] = hn;
    }
    // ---- publish: per-wave LDS transpose -> 8B stores -> barrier -> block flag ----
    if (ti < 127){
      #pragma unroll
      for (int r=0;r<4;r++) sXw[(sg*4 + r)*16 + fl] = (f16)hstate[r];
      asm volatile("s_waitcnt lgkmcnt(0)" ::: "memory");   // wave-local ds ordering
      u64 v = *(const u64*)&sXw[prow*16 + pf];
      f16* hb = hbuf + ((size_t)gidx*2 + ((ti&1)^1))*(16*512);
      __hip_atomic_store((u64*)(hb + (size_t)prow*512 + fbase + pf), v,
                         __ATOMIC_RELAXED, __HIP_MEMORY_SCOPE_AGENT);
      __syncthreads();            // all 4 waves drain vmcnt(0): publishes acked
      if (tid == 0)
        __hip_atomic_store(myflag, (unsigned)(ti+1),
                           __ATOMIC_RELAXED, __HIP_MEMORY_SCOPE_AGENT);
    }
    // ---- outputs (after the flag, off the critical path) ----
    #pragma unroll
    for (int r=0;r<4;r++)
      out[((size_t)(t*B_ + mb + r))*1024 + dir*512 + fbase + fl] = hstate[r];
    if (dir==1 && t==0){
      #pragma unroll
      for (int r=0;r<4;r++)
        out2[(size_t)(mb + r)*512 + fbase + fl] = hstate[r];
    }
  }
}

extern "C" void kernel_launch(void* const* d_in, const int* in_sizes, int n_in,
                              void* d_out, int out_size, void* d_ws, size_t ws_size,
                              hipStream_t stream){
  const int*   xs      = (const int*)  d_in[0];
  const float* xs_mask = (const float*)d_in[1];
  const float* emb     = (const float*)d_in[2];
  const float* Wx_f    = (const float*)d_in[3];
  const float* Wh_f    = (const float*)d_in[4];
  const float* b_f     = (const float*)d_in[5];
  const float* Wx_b    = (const float*)d_in[6];
  const float* Wh_b    = (const float*)d_in[7];
  const float* b_b     = (const float*)d_in[8];

  char* w = (char*)d_ws;
  f16*      Xe    = (f16*)(w);                  //  8,388,608 B
  f16*      WxT   = (f16*)(w + 8388608);        //  3,145,728 B
  f16*      WhT   = (f16*)(w + 11534336);       //  3,145,728 B
  f16*      xw2   = (f16*)(w + 14680064);       // 50,331,648 B
  f16*      hbuf  = (f16*)(w + 65011712);       //    262,144 B (8 groups x 2 x 16KB)
  unsigned* flags = (unsigned*)(w + 65273856);  //      8,192 B (64 flags x 64B)
  float*    out   = (float*)d_out;

  k_embed    <<<dim3(4096),    dim3(256), 0, stream>>>(xs, emb, Xe, (uint4*)flags);
  k_transpose<<<dim3(24,8,4),  dim3(256), 0, stream>>>(Wx_f, Wx_b, Wh_f, Wh_b, WxT, WhT);
  k_gemm     <<<dim3(24,64),   dim3(256), 0, stream>>>(Xe, WxT, b_f, b_b, xw2);
  k_scan     <<<dim3(64),      dim3(256), 0, stream>>>(xw2, WhT, hbuf, xs_mask, out, flags);
}

// Round 18
// 712.794 us; speedup vs baseline: 1.0177x; 1.0177x over previous
//
#include <hip/hip_runtime.h>
#include <stdint.h>

typedef _Float16 f16;
typedef _Float16 f16x8 __attribute__((ext_vector_type(8)));
typedef float    f32x4 __attribute__((ext_vector_type(4)));
typedef unsigned long long u64;

#define L_    128
#define B_    64
#define E_    512
#define H_    512
#define G3    1536   // 3*H
#define NCOL  3072   // 2*3H

__device__ __forceinline__ float sigm_(float x){ return 1.0f/(1.0f + __expf(-x)); }
__device__ __forceinline__ float tanh_(float x){ return 1.0f - 2.0f/(__expf(2.0f*x) + 1.0f); }

// ---------------- P1: embedding gather, f32 -> f16 (+ flag zeroing in block 0) ----------------
__global__ __launch_bounds__(256) void k_embed(const int* __restrict__ xs,
                                               const float* __restrict__ emb,
                                               f16* __restrict__ Xe,
                                               uint4* __restrict__ flags4){
  if (blockIdx.x == 0){
    flags4[threadIdx.x]       = make_uint4(0,0,0,0);   // 4KB
    flags4[256 + threadIdx.x] = make_uint4(0,0,0,0);   // 8KB total
  }
  int row = blockIdx.x*2 + (threadIdx.x >> 7);       // 2 rows / block
  int c   = (threadIdx.x & 127) * 4;
  int idx = xs[row];
  float4 v = *(const float4*)(emb + (size_t)idx*E_ + c);
  union { f16 h[4]; uint2 u; } p;
  p.h[0] = (f16)v.x; p.h[1] = (f16)v.y; p.h[2] = (f16)v.z; p.h[3] = (f16)v.w;
  *(uint2*)(Xe + (size_t)row*E_ + c) = p.u;
}

// ---------------- P2: transpose+cast 4 weight matrices (512x1536 f32 -> 1536x512 f16) ----------------
__global__ __launch_bounds__(256) void k_transpose(const float* __restrict__ Wx_f, const float* __restrict__ Wx_b,
                                                   const float* __restrict__ Wh_f, const float* __restrict__ Wh_b,
                                                   f16* __restrict__ WxT, f16* __restrict__ WhT){
  int mat = blockIdx.z;
  const float* src = mat==0 ? Wx_f : mat==1 ? Wx_b : mat==2 ? Wh_f : Wh_b;
  f16* dst = (mat < 2) ? (WxT + (size_t)mat*G3*E_) : (WhT + (size_t)(mat-2)*G3*H_);
  int n0 = blockIdx.x*64, k0 = blockIdx.y*64;
  __shared__ f16 tile[64][65];
  int tid = threadIdx.x;
  for (int i=0;i<16;i++){
    int r = i*4 + (tid>>6);      // k
    int c = tid & 63;            // n
    tile[r][c] = (f16)src[(size_t)(k0+r)*G3 + n0 + c];
  }
  __syncthreads();
  for (int i=0;i<16;i++){
    int n = i*4 + (tid>>6);
    int k = tid & 63;
    dst[(size_t)(n0+n)*512 + k0 + k] = tile[k][n];
  }
}

// ---------------- G: xw2[t][col][b] = (Xe @ WxT^T + bias), f16 MFMA 128x128 tiles ----------------
__global__ __launch_bounds__(256) void k_gemm(const f16* __restrict__ Xe, const f16* __restrict__ WxT,
                                              const float* __restrict__ bf, const float* __restrict__ bb,
                                              f16* __restrict__ xw2){
  __shared__ __align__(16) f16 sA[128*32];
  __shared__ __align__(16) f16 sB[128*32];
  const int tid = threadIdx.x;
  const int l = tid & 63, w = tid >> 6;
  const int wr = w >> 1, wc = w & 1;
  const int m0 = blockIdx.y*128, n0 = blockIdx.x*128;
  const int rl = l & 15, sg = l >> 4;
  f32x4 acc[4][4] = {};
  for (int kk=0; kk<16; ++kk){
    __syncthreads();
    for (int i=0;i<2;i++){
      int c = i*256 + tid; int row = c>>2, s = c&3;
      int sw = s ^ ((row>>1)&3);                       // bank-swizzle for 64B rows
      *(uint4*)&sA[row*32 + sw*8] = *(const uint4*)(Xe  + (size_t)(m0+row)*512 + kk*32 + s*8);
      *(uint4*)&sB[row*32 + sw*8] = *(const uint4*)(WxT + (size_t)(n0+row)*512 + kk*32 + s*8);
    }
    __syncthreads();
    f16x8 a[4], b[4];
    for (int mi=0;mi<4;mi++){ int m=(wr*4+mi)*16+rl; a[mi] = *(const f16x8*)&sA[m*32 + ((sg^((m>>1)&3))*8)]; }
    for (int nj=0;nj<4;nj++){ int n=(wc*4+nj)*16+rl; b[nj] = *(const f16x8*)&sB[n*32 + ((sg^((n>>1)&3))*8)]; }
    for (int mi=0;mi<4;mi++)
      for (int nj=0;nj<4;nj++)
        acc[mi][nj] = __builtin_amdgcn_mfma_f32_16x16x32_f16(a[mi], b[nj], acc[mi][nj], 0,0,0);
  }
  // epilogue: write transposed layout xw2[t][n][b] (b fastest, 64 per (t,n))
  for (int nj=0;nj<4;nj++){
    int n = n0 + (wc*4+nj)*16 + rl;
    float bias = (n < G3) ? bf[n] : bb[n-G3];
    for (int mi=0;mi<4;mi++){
      int sub = (wr*4+mi)*16 + sg*4;       // row within 128-tile
      int t   = (m0 + sub) >> 6;
      int b0  = sub & 63;
      union { f16 h[4]; uint2 u; } p;
      for (int r=0;r<4;r++) p.h[r] = (f16)(acc[mi][nj][r] + bias);
      *(uint2*)(xw2 + ((size_t)t*NCOL + n)*B_ + b0) = p.u;
    }
  }
}

// ---------------- S: bidirectional GRU scan, 1-wave blocks (no barriers at all) ----------------
// grid = 256 blocks x 64 threads (1 block/CU): dir = bx>>7, m = (bx>>5)&3 (batch tile
// of 16 rows), n = bx&31 (feature slice of 16). Group (dir,m) = 32 single-wave
// producers. Per-step: poll 32 flags -> 32 atomic 8B h-loads -> 48 MFMA (pinned Wh)
// -> gates -> wave-local 512B LDS transpose (lgkmcnt only) -> 8B publishes -> OWN
// vmcnt(0) -> OWN flag. Zero __syncthreads in the loop; zero inter-wave coupling
// inside a block. Tests waves-per-CU (Reading 1) vs fan-in (Reading 2).
// Flags: 32B slots, index (n*8+gidx): one group's 32 flags on 32 distinct lines;
// same-line slots belong to different (independently drifting) groups.
__global__ __launch_bounds__(64, 1) void k_scan(const f16* __restrict__ xw2, const f16* __restrict__ WhT,
                                                f16* __restrict__ hbuf, const float* __restrict__ mask,
                                                float* __restrict__ out, unsigned* __restrict__ flags){
  const int dir = blockIdx.x >> 7;
  const int m   = (blockIdx.x >> 5) & 3;
  const int n   = blockIdx.x & 31;
  const int gidx = dir*4 + m;                 // sync group (8 total)
  __shared__ __align__(16) f16 sX[16*16];     // 512B transpose scratch (one wave)
  const int l = threadIdx.x & 63;
  const int fl = l & 15, sg = l >> 4;
  const int fbase = n*16;                     // this wave's 16 features (within 512)
  // one-time: 48 B-fragments (Wh cols for z,r,h of our features) direct from global, pinned
  f16x8 pz[16], pr[16], ph[16];
  {
    const f16* wb = WhT + (size_t)dir*G3*512;
    #pragma unroll
    for (int kk=0;kk<16;kk++){
      int ko = kk*32 + sg*8;
      pz[kk] = *(const f16x8*)(wb + (size_t)(       fbase + fl)*512 + ko);
      pr[kk] = *(const f16x8*)(wb + (size_t)( 512 + fbase + fl)*512 + ko);
      ph[kk] = *(const f16x8*)(wb + (size_t)(1024 + fbase + fl)*512 + ko);
    }
  }
  #pragma unroll
  for (int kk=0;kk<16;kk++){
    asm volatile("" : "+v"(pz[kk]));
    asm volatile("" : "+v"(pr[kk]));
    asm volatile("" : "+v"(ph[kk]));
  }
  float hstate[4] = {0.f,0.f,0.f,0.f};
  float* out2 = out + (size_t)L_*B_*1024;
  const int mb = m*16 + sg*4;                 // absolute batch base of this lane's C rows
  unsigned* myflag = flags + (size_t)(n*8 + gidx)*8;                   // 32B slots
  const unsigned* pollp = flags + (size_t)((l&31)*8 + gidx)*8;         // 32 group flags
  const int prow = l >> 2, pf = (l & 3)*4;    // publish mapping after transpose

  for (int ti=0; ti<128; ++ti){
    const int t = dir ? (127 - ti) : ti;
    // ---- prefetch xw gates + mask (independent of h; hides under poll) ----
    size_t xb = ((size_t)t*NCOL + dir*G3 + fbase + fl)*B_ + mb;
    union { uint2 u; f16 h[4]; } xzv, xrv, xhv;
    xzv.u = *(const uint2*)(xw2 + xb);
    xrv.u = *(const uint2*)(xw2 + xb + (size_t)512*B_);
    xhv.u = *(const uint2*)(xw2 + xb + (size_t)1024*B_);
    float4 mv4 = *(const float4*)(mask + t*B_ + mb);
    // ---- wait for previous step's h (this group only), then hw = h @ Wh ----
    f32x4 az = {0,0,0,0}, ar = {0,0,0,0}, ah = {0,0,0,0};
    if (ti){
      unsigned tgt = (unsigned)ti;
      while (true){
        unsigned f = __hip_atomic_load(pollp, __ATOMIC_RELAXED, __HIP_MEMORY_SCOPE_AGENT);
        if (__all((int)(f >= tgt))) break;
      }
      // group h buffer: 16 rows x 512 f16; A-row = batch-within-tile = fl; row = 128 u64
      const u64* hq = (const u64*)(hbuf + ((size_t)gidx*2 + (ti&1))*(16*512)) + (size_t)fl*128;
      u64 q[32];
      #pragma unroll
      for (int kk=0;kk<16;kk++){
        int j = kk*8 + sg*2;                // == (kk*4+sg)*2
        q[2*kk  ] = __hip_atomic_load(hq + j,     __ATOMIC_RELAXED, __HIP_MEMORY_SCOPE_AGENT);
        q[2*kk+1] = __hip_atomic_load(hq + j + 1, __ATOMIC_RELAXED, __HIP_MEMORY_SCOPE_AGENT);
      }
      #pragma unroll
      for (int kk=0;kk<16;kk++){
        union { u64 d[2]; f16x8 h; } a;
        a.d[0] = q[2*kk]; a.d[1] = q[2*kk+1];
        az = __builtin_amdgcn_mfma_f32_16x16x32_f16(a.h, pz[kk], az, 0,0,0);
        ar = __builtin_amdgcn_mfma_f32_16x16x32_f16(a.h, pr[kk], ar, 0,0,0);
        ah = __builtin_amdgcn_mfma_f32_16x16x32_f16(a.h, ph[kk], ah, 0,0,0);
      }
    }
    // ---- gates + state update (lane = feature fbase+fl, batch rows mb..mb+3) ----
    #pragma unroll
    for (int r=0;r<4;r++){
      float z  = sigm_((float)xzv.h[r] + az[r]);
      float rr = sigm_((float)xrv.h[r] + ar[r]);
      float ht = tanh_((float)xhv.h[r] + rr*ah[r]);
      float mv = (&mv4.x)[r];
      float hn = (1.0f - z)*hstate[r] + z*ht;
      hn = mv*hn + (1.0f - mv)*hstate[r];
      hstate[r] = hn;
    }
    // ---- publish: wave-local LDS transpose -> 8B stores -> own vmcnt(0) -> own flag ----
    if (ti < 127){
      #pragma unroll
      for (int r=0;r<4;r++) sX[(sg*4 + r)*16 + fl] = (f16)hstate[r];
      asm volatile("s_waitcnt lgkmcnt(0)" ::: "memory");   // wave-local ds ordering
      u64 v = *(const u64*)&sX[prow*16 + pf];
      f16* hb = hbuf + ((size_t)gidx*2 + ((ti&1)^1))*(16*512);
      __hip_atomic_store((u64*)(hb + (size_t)prow*512 + fbase + pf), v,
                         __ATOMIC_RELAXED, __HIP_MEMORY_SCOPE_AGENT);
      asm volatile("s_waitcnt vmcnt(0)" ::: "memory");     // own-wave stores acked
      if (l == 0)
        __hip_atomic_store(myflag, (unsigned)(ti+1),
                           __ATOMIC_RELAXED, __HIP_MEMORY_SCOPE_AGENT);
    }
    // ---- outputs (after the flag, off the critical path) ----
    #pragma unroll
    for (int r=0;r<4;r++)
      out[((size_t)(t*B_ + mb + r))*1024 + dir*512 + fbase + fl] = hstate[r];
    if (dir==1 && t==0){
      #pragma unroll
      for (int r=0;r<4;r++)
        out2[(size_t)(mb + r)*512 + fbase + fl] = hstate[r];
    }
  }
}

extern "C" void kernel_launch(void* const* d_in, const int* in_sizes, int n_in,
                              void* d_out, int out_size, void* d_ws, size_t ws_size,
                              hipStream_t stream){
  const int*   xs      = (const int*)  d_in[0];
  const float* xs_mask = (const float*)d_in[1];
  const float* emb     = (const float*)d_in[2];
  const float* Wx_f    = (const float*)d_in[3];
  const float* Wh_f    = (const float*)d_in[4];
  const float* b_f     = (const float*)d_in[5];
  const float* Wx_b    = (const float*)d_in[6];
  const float* Wh_b    = (const float*)d_in[7];
  const float* b_b     = (const float*)d_in[8];

  char* w = (char*)d_ws;
  f16*      Xe    = (f16*)(w);                  //  8,388,608 B
  f16*      WxT   = (f16*)(w + 8388608);        //  3,145,728 B
  f16*      WhT   = (f16*)(w + 11534336);       //  3,145,728 B
  f16*      xw2   = (f16*)(w + 14680064);       // 50,331,648 B
  f16*      hbuf  = (f16*)(w + 65011712);       //    262,144 B (8 groups x 2 x 16KB)
  unsigned* flags = (unsigned*)(w + 65273856);  //      8,192 B (256 flags x 32B)
  float*    out   = (float*)d_out;

  k_embed    <<<dim3(4096),    dim3(256), 0, stream>>>(xs, emb, Xe, (uint4*)flags);
  k_transpose<<<dim3(24,8,4),  dim3(256), 0, stream>>>(Wx_f, Wx_b, Wh_f, Wh_b, WxT, WhT);
  k_gemm     <<<dim3(24,64),   dim3(256), 0, stream>>>(Xe, WxT, b_f, b_b, xw2);
  k_scan     <<<dim3(256),     dim3(64),  0, stream>>>(xw2, WhT, hbuf, xs_mask, out, flags);
}

// Round 19
// 620.375 us; speedup vs baseline: 1.1693x; 1.1490x over previous
//
#include <hip/hip_runtime.h>
#include <stdint.h>

typedef _Float16 f16;
typedef _Float16 f16x8 __attribute__((ext_vector_type(8)));
typedef float    f32x4 __attribute__((ext_vector_type(4)));
typedef unsigned long long u64;

#define L_    128
#define B_    64
#define E_    512
#define H_    512
#define G3    1536   // 3*H
#define NCOL  3072   // 2*3H

__device__ __forceinline__ float sigm_(float x){ return 1.0f/(1.0f + __expf(-x)); }
__device__ __forceinline__ float tanh_(float x){ return 1.0f - 2.0f/(__expf(2.0f*x) + 1.0f); }

// ---------------- P1: embedding gather, f32 -> f16 (+ flag zeroing in block 0) ----------------
__global__ __launch_bounds__(256) void k_embed(const int* __restrict__ xs,
                                               const float* __restrict__ emb,
                                               f16* __restrict__ Xe,
                                               uint4* __restrict__ flags4){
  if (blockIdx.x == 0){
    flags4[threadIdx.x]       = make_uint4(0,0,0,0);   // 4KB
    flags4[256 + threadIdx.x] = make_uint4(0,0,0,0);   // 8KB total
  }
  int row = blockIdx.x*2 + (threadIdx.x >> 7);       // 2 rows / block
  int c   = (threadIdx.x & 127) * 4;
  int idx = xs[row];
  float4 v = *(const float4*)(emb + (size_t)idx*E_ + c);
  union { f16 h[4]; uint2 u; } p;
  p.h[0] = (f16)v.x; p.h[1] = (f16)v.y; p.h[2] = (f16)v.z; p.h[3] = (f16)v.w;
  *(uint2*)(Xe + (size_t)row*E_ + c) = p.u;
}

// ---------------- P2: transpose+cast 4 weight matrices (512x1536 f32 -> 1536x512 f16) ----------------
__global__ __launch_bounds__(256) void k_transpose(const float* __restrict__ Wx_f, const float* __restrict__ Wx_b,
                                                   const float* __restrict__ Wh_f, const float* __restrict__ Wh_b,
                                                   f16* __restrict__ WxT, f16* __restrict__ WhT){
  int mat = blockIdx.z;
  const float* src = mat==0 ? Wx_f : mat==1 ? Wx_b : mat==2 ? Wh_f : Wh_b;
  f16* dst = (mat < 2) ? (WxT + (size_t)mat*G3*E_) : (WhT + (size_t)(mat-2)*G3*H_);
  int n0 = blockIdx.x*64, k0 = blockIdx.y*64;
  __shared__ f16 tile[64][65];
  int tid = threadIdx.x;
  for (int i=0;i<16;i++){
    int r = i*4 + (tid>>6);      // k
    int c = tid & 63;            // n
    tile[r][c] = (f16)src[(size_t)(k0+r)*G3 + n0 + c];
  }
  __syncthreads();
  for (int i=0;i<16;i++){
    int n = i*4 + (tid>>6);
    int k = tid & 63;
    dst[(size_t)(n0+n)*512 + k0 + k] = tile[k][n];
  }
}

// ---------------- G: xw2[t][col][b] = (Xe @ WxT^T + bias), f16 MFMA 128x128 tiles ----------------
__global__ __launch_bounds__(256) void k_gemm(const f16* __restrict__ Xe, const f16* __restrict__ WxT,
                                              const float* __restrict__ bf, const float* __restrict__ bb,
                                              f16* __restrict__ xw2){
  __shared__ __align__(16) f16 sA[128*32];
  __shared__ __align__(16) f16 sB[128*32];
  const int tid = threadIdx.x;
  const int l = tid & 63, w = tid >> 6;
  const int wr = w >> 1, wc = w & 1;
  const int m0 = blockIdx.y*128, n0 = blockIdx.x*128;
  const int rl = l & 15, sg = l >> 4;
  f32x4 acc[4][4] = {};
  for (int kk=0; kk<16; ++kk){
    __syncthreads();
    for (int i=0;i<2;i++){
      int c = i*256 + tid; int row = c>>2, s = c&3;
      int sw = s ^ ((row>>1)&3);                       // bank-swizzle for 64B rows
      *(uint4*)&sA[row*32 + sw*8] = *(const uint4*)(Xe  + (size_t)(m0+row)*512 + kk*32 + s*8);
      *(uint4*)&sB[row*32 + sw*8] = *(const uint4*)(WxT + (size_t)(n0+row)*512 + kk*32 + s*8);
    }
    __syncthreads();
    f16x8 a[4], b[4];
    for (int mi=0;mi<4;mi++){ int m=(wr*4+mi)*16+rl; a[mi] = *(const f16x8*)&sA[m*32 + ((sg^((m>>1)&3))*8)]; }
    for (int nj=0;nj<4;nj++){ int n=(wc*4+nj)*16+rl; b[nj] = *(const f16x8*)&sB[n*32 + ((sg^((n>>1)&3))*8)]; }
    for (int mi=0;mi<4;mi++)
      for (int nj=0;nj<4;nj++)
        acc[mi][nj] = __builtin_amdgcn_mfma_f32_16x16x32_f16(a[mi], b[nj], acc[mi][nj], 0,0,0);
  }
  // epilogue: write transposed layout xw2[t][n][b] (b fastest, 64 per (t,n))
  for (int nj=0;nj<4;nj++){
    int n = n0 + (wc*4+nj)*16 + rl;
    float bias = (n < G3) ? bf[n] : bb[n-G3];
    for (int mi=0;mi<4;mi++){
      int sub = (wr*4+mi)*16 + sg*4;       // row within 128-tile
      int t   = (m0 + sub) >> 6;
      int b0  = sub & 63;
      union { f16 h[4]; uint2 u; } p;
      for (int r=0;r<4;r++) p.h[r] = (f16)(acc[mi][nj][r] + bias);
      *(uint2*)(xw2 + ((size_t)t*NCOL + n)*B_ + b0) = p.u;
    }
  }
}

// ---------------- S: bidirectional GRU scan — rd16 base + poll backoff ----------------
// grid = 128 blocks x 128 threads: dir = bx>>6, m = (bx>>4)&3 (batch tile of 16 rows),
// n = bx&15 (feature slice of 32). Group (dir,m) = 16 producers. Pinned Wh fragments
// (global->regs once). Per-step: poll 16 flags (s_sleep(1) backoff on miss to cut the
// L3 poll storm) -> 32 atomic 8B h-loads -> 48 MFMA -> gates -> per-wave 16x16 LDS
// transpose -> 8B publishes -> 2-wave barrier (drains vmcnt) -> per-block flag.
__global__ __launch_bounds__(128, 1) void k_scan(const f16* __restrict__ xw2, const f16* __restrict__ WhT,
                                                 f16* __restrict__ hbuf, const float* __restrict__ mask,
                                                 float* __restrict__ out, unsigned* __restrict__ flags){
  const int dir = blockIdx.x >> 6;
  const int m   = (blockIdx.x >> 4) & 3;
  const int n   = blockIdx.x & 15;
  const int gidx = dir*4 + m;                 // sync group (8 total)
  __shared__ __align__(16) f16 sX[2*16*16];   // 1KB: per-wave 16x16 transpose scratch
  const int tid = threadIdx.x, l = tid & 63, wv = tid >> 6;   // wv in {0,1}
  const int fl = l & 15, sg = l >> 4;
  const int fbase = n*32 + wv*16;             // this wave's 16 features (within 512)
  // one-time: 48 B-fragments (Wh cols for z,r,h of our features) direct from global, pinned
  f16x8 pz[16], pr[16], ph[16];
  {
    const f16* wb = WhT + (size_t)dir*G3*512;
    #pragma unroll
    for (int kk=0;kk<16;kk++){
      int ko = kk*32 + sg*8;
      pz[kk] = *(const f16x8*)(wb + (size_t)(       fbase + fl)*512 + ko);
      pr[kk] = *(const f16x8*)(wb + (size_t)( 512 + fbase + fl)*512 + ko);
      ph[kk] = *(const f16x8*)(wb + (size_t)(1024 + fbase + fl)*512 + ko);
    }
  }
  #pragma unroll
  for (int kk=0;kk<16;kk++){
    asm volatile("" : "+v"(pz[kk]));
    asm volatile("" : "+v"(pr[kk]));
    asm volatile("" : "+v"(ph[kk]));
  }
  float hstate[4] = {0.f,0.f,0.f,0.f};
  float* out2 = out + (size_t)L_*B_*1024;
  const int mb = m*16 + sg*4;                 // absolute batch base of this lane's C rows
  unsigned* myflag = flags + (size_t)(n*8 + gidx)*16;                  // 64B-strided
  const unsigned* pollp = flags + (size_t)((l&15)*8 + gidx)*16;        // 16 group flags
  f16* const sXw = &sX[wv*256];               // this wave's 512B transpose tile
  const int prow = l >> 2, pf = (l & 3)*4;    // publish mapping after transpose

  for (int ti=0; ti<128; ++ti){
    const int t = dir ? (127 - ti) : ti;
    // ---- prefetch xw gates + mask (independent of h; hides under poll) ----
    size_t xb = ((size_t)t*NCOL + dir*G3 + fbase + fl)*B_ + mb;
    union { uint2 u; f16 h[4]; } xzv, xrv, xhv;
    xzv.u = *(const uint2*)(xw2 + xb);
    xrv.u = *(const uint2*)(xw2 + xb + (size_t)512*B_);
    xhv.u = *(const uint2*)(xw2 + xb + (size_t)1024*B_);
    float4 mv4 = *(const float4*)(mask + t*B_ + mb);
    // ---- wait for previous step's h (this group only), then hw = h @ Wh ----
    f32x4 az = {0,0,0,0}, ar = {0,0,0,0}, ah = {0,0,0,0};
    if (ti){
      unsigned tgt = (unsigned)ti;
      while (true){
        unsigned f = __hip_atomic_load(pollp, __ATOMIC_RELAXED, __HIP_MEMORY_SCOPE_AGENT);
        if (__all((int)(f >= tgt))) break;
        __builtin_amdgcn_s_sleep(1);          // backoff: cut poll-line traffic ~4x
      }
      // group h buffer: 16 rows x 512 f16; A-row = batch-within-tile = fl; row = 128 u64
      const u64* hq = (const u64*)(hbuf + ((size_t)gidx*2 + (ti&1))*(16*512)) + (size_t)fl*128;
      u64 q[32];
      #pragma unroll
      for (int kk=0;kk<16;kk++){
        int j = kk*8 + sg*2;                // == (kk*4+sg)*2
        q[2*kk  ] = __hip_atomic_load(hq + j,     __ATOMIC_RELAXED, __HIP_MEMORY_SCOPE_AGENT);
        q[2*kk+1] = __hip_atomic_load(hq + j + 1, __ATOMIC_RELAXED, __HIP_MEMORY_SCOPE_AGENT);
      }
      #pragma unroll
      for (int kk=0;kk<16;kk++){
        union { u64 d[2]; f16x8 h; } a;
        a.d[0] = q[2*kk]; a.d[1] = q[2*kk+1];
        az = __builtin_amdgcn_mfma_f32_16x16x32_f16(a.h, pz[kk], az, 0,0,0);
        ar = __builtin_amdgcn_mfma_f32_16x16x32_f16(a.h, pr[kk], ar, 0,0,0);
        ah = __builtin_amdgcn_mfma_f32_16x16x32_f16(a.h, ph[kk], ah, 0,0,0);
      }
    }
    // ---- gates + state update (lane = feature fbase+fl, batch rows mb..mb+3) ----
    #pragma unroll
    for (int r=0;r<4;r++){
      float z  = sigm_((float)xzv.h[r] + az[r]);
      float rr = sigm_((float)xrv.h[r] + ar[r]);
      float ht = tanh_((float)xhv.h[r] + rr*ah[r]);
      float mv = (&mv4.x)[r];
      float hn = (1.0f - z)*hstate[r] + z*ht;
      hn = mv*hn + (1.0f - mv)*hstate[r];
      hstate[r] = hn;
    }
    // ---- publish: per-wave LDS transpose -> 8B stores -> barrier -> block flag ----
    if (ti < 127){
      #pragma unroll
      for (int r=0;r<4;r++) sXw[(sg*4 + r)*16 + fl] = (f16)hstate[r];
      asm volatile("s_waitcnt lgkmcnt(0)" ::: "memory");   // wave-local ds ordering
      u64 v = *(const u64*)&sXw[prow*16 + pf];
      f16* hb = hbuf + ((size_t)gidx*2 + ((ti&1)^1))*(16*512);
      __hip_atomic_store((u64*)(hb + (size_t)prow*512 + n*32 + wv*16 + pf), v,
                         __ATOMIC_RELAXED, __HIP_MEMORY_SCOPE_AGENT);
      __syncthreads();            // both waves drain vmcnt(0): publishes acked
      if (tid == 0)
        __hip_atomic_store(myflag, (unsigned)(ti+1),
                           __ATOMIC_RELAXED, __HIP_MEMORY_SCOPE_AGENT);
    }
    // ---- outputs (after the flag, off the critical path) ----
    #pragma unroll
    for (int r=0;r<4;r++)
      out[((size_t)(t*B_ + mb + r))*1024 + dir*512 + fbase + fl] = hstate[r];
    if (dir==1 && t==0){
      #pragma unroll
      for (int r=0;r<4;r++)
        out2[(size_t)(mb + r)*512 + fbase + fl] = hstate[r];
    }
  }
}

extern "C" void kernel_launch(void* const* d_in, const int* in_sizes, int n_in,
                              void* d_out, int out_size, void* d_ws, size_t ws_size,
                              hipStream_t stream){
  const int*   xs      = (const int*)  d_in[0];
  const float* xs_mask = (const float*)d_in[1];
  const float* emb     = (const float*)d_in[2];
  const float* Wx_f    = (const float*)d_in[3];
  const float* Wh_f    = (const float*)d_in[4];
  const float* b_f     = (const float*)d_in[5];
  const float* Wx_b    = (const float*)d_in[6];
  const float* Wh_b    = (const float*)d_in[7];
  const float* b_b     = (const float*)d_in[8];

  char* w = (char*)d_ws;
  f16*      Xe    = (f16*)(w);                  //  8,388,608 B
  f16*      WxT   = (f16*)(w + 8388608);        //  3,145,728 B
  f16*      WhT   = (f16*)(w + 11534336);       //  3,145,728 B
  f16*      xw2   = (f16*)(w + 14680064);       // 50,331,648 B
  f16*      hbuf  = (f16*)(w + 65011712);       //    262,144 B (8 groups x 2 x 16KB)
  unsigned* flags = (unsigned*)(w + 65273856);  //      8,192 B (128 flags x 64B)
  float*    out   = (float*)d_out;

  k_embed    <<<dim3(4096),    dim3(256), 0, stream>>>(xs, emb, Xe, (uint4*)flags);
  k_transpose<<<dim3(24,8,4),  dim3(256), 0, stream>>>(Wx_f, Wx_b, Wh_f, Wh_b, WxT, WhT);
  k_gemm     <<<dim3(24,64),   dim3(256), 0, stream>>>(Xe, WxT, b_f, b_b, xw2);
  k_scan     <<<dim3(128),     dim3(128), 0, stream>>>(xw2, WhT, hbuf, xs_mask, out, flags);
}

// Round 22
// 610.307 us; speedup vs baseline: 1.1886x; 1.0165x over previous
//
#include <hip/hip_runtime.h>
#include <stdint.h>

typedef _Float16 f16;
typedef _Float16 f16x8 __attribute__((ext_vector_type(8)));
typedef float    f32x4 __attribute__((ext_vector_type(4)));
typedef unsigned long long u64;

#define L_    128
#define B_    64
#define E_    512
#define H_    512
#define G3    1536   // 3*H
#define NCOL  3072   // 2*3H

__device__ __forceinline__ float sigm_(float x){ return 1.0f/(1.0f + __expf(-x)); }
__device__ __forceinline__ float tanh_(float x){ return 1.0f - 2.0f/(__expf(2.0f*x) + 1.0f); }

// ---------------- P1: embedding gather, f32 -> f16 (+ flag zeroing in block 0) ----------------
__global__ __launch_bounds__(256) void k_embed(const int* __restrict__ xs,
                                               const float* __restrict__ emb,
                                               f16* __restrict__ Xe,
                                               uint4* __restrict__ flags4){
  if (blockIdx.x == 0){
    flags4[threadIdx.x]       = make_uint4(0,0,0,0);   // 4KB
    flags4[256 + threadIdx.x] = make_uint4(0,0,0,0);   // 8KB total
  }
  int row = blockIdx.x*2 + (threadIdx.x >> 7);       // 2 rows / block
  int c   = (threadIdx.x & 127) * 4;
  int idx = xs[row];
  float4 v = *(const float4*)(emb + (size_t)idx*E_ + c);
  union { f16 h[4]; uint2 u; } p;
  p.h[0] = (f16)v.x; p.h[1] = (f16)v.y; p.h[2] = (f16)v.z; p.h[3] = (f16)v.w;
  *(uint2*)(Xe + (size_t)row*E_ + c) = p.u;
}

// ---------------- P2: transpose+cast 4 weight matrices (512x1536 f32 -> 1536x512 f16) ----------------
__global__ __launch_bounds__(256) void k_transpose(const float* __restrict__ Wx_f, const float* __restrict__ Wx_b,
                                                   const float* __restrict__ Wh_f, const float* __restrict__ Wh_b,
                                                   f16* __restrict__ WxT, f16* __restrict__ WhT){
  int mat = blockIdx.z;
  const float* src = mat==0 ? Wx_f : mat==1 ? Wx_b : mat==2 ? Wh_f : Wh_b;
  f16* dst = (mat < 2) ? (WxT + (size_t)mat*G3*E_) : (WhT + (size_t)(mat-2)*G3*H_);
  int n0 = blockIdx.x*64, k0 = blockIdx.y*64;
  __shared__ f16 tile[64][65];
  int tid = threadIdx.x;
  for (int i=0;i<16;i++){
    int r = i*4 + (tid>>6);      // k
    int c = tid & 63;            // n
    tile[r][c] = (f16)src[(size_t)(k0+r)*G3 + n0 + c];
  }
  __syncthreads();
  for (int i=0;i<16;i++){
    int n = i*4 + (tid>>6);
    int k = tid & 63;
    dst[(size_t)(n0+n)*512 + k0 + k] = tile[k][n];
  }
}

// ---------------- G: xw2[t][col][b] = (Xe @ WxT^T + bias), f16 MFMA 128x128 tiles ----------------
__global__ __launch_bounds__(256) void k_gemm(const f16* __restrict__ Xe, const f16* __restrict__ WxT,
                                              const float* __restrict__ bf, const float* __restrict__ bb,
                                              f16* __restrict__ xw2){
  __shared__ __align__(16) f16 sA[128*32];
  __shared__ __align__(16) f16 sB[128*32];
  const int tid = threadIdx.x;
  const int l = tid & 63, w = tid >> 6;
  const int wr = w >> 1, wc = w & 1;
  const int m0 = blockIdx.y*128, n0 = blockIdx.x*128;
  const int rl = l & 15, sg = l >> 4;
  f32x4 acc[4][4] = {};
  for (int kk=0; kk<16; ++kk){
    __syncthreads();
    for (int i=0;i<2;i++){
      int c = i*256 + tid; int row = c>>2, s = c&3;
      int sw = s ^ ((row>>1)&3);                       // bank-swizzle for 64B rows
      *(uint4*)&sA[row*32 + sw*8] = *(const uint4*)(Xe  + (size_t)(m0+row)*512 + kk*32 + s*8);
      *(uint4*)&sB[row*32 + sw*8] = *(const uint4*)(WxT + (size_t)(n0+row)*512 + kk*32 + s*8);
    }
    __syncthreads();
    f16x8 a[4], b[4];
    for (int mi=0;mi<4;mi++){ int m=(wr*4+mi)*16+rl; a[mi] = *(const f16x8*)&sA[m*32 + ((sg^((m>>1)&3))*8)]; }
    for (int nj=0;nj<4;nj++){ int n=(wc*4+nj)*16+rl; b[nj] = *(const f16x8*)&sB[n*32 + ((sg^((n>>1)&3))*8)]; }
    for (int mi=0;mi<4;mi++)
      for (int nj=0;nj<4;nj++)
        acc[mi][nj] = __builtin_amdgcn_mfma_f32_16x16x32_f16(a[mi], b[nj], acc[mi][nj], 0,0,0);
  }
  // epilogue: write transposed layout xw2[t][n][b] (b fastest, 64 per (t,n))
  for (int nj=0;nj<4;nj++){
    int n = n0 + (wc*4+nj)*16 + rl;
    float bias = (n < G3) ? bf[n] : bb[n-G3];
    for (int mi=0;mi<4;mi++){
      int sub = (wr*4+mi)*16 + sg*4;       // row within 128-tile
      int t   = (m0 + sub) >> 6;
      int b0  = sub & 63;
      union { f16 h[4]; uint2 u; } p;
      for (int r=0;r<4;r++) p.h[r] = (f16)(acc[mi][nj][r] + bias);
      *(uint2*)(xw2 + ((size_t)t*NCOL + n)*B_ + b0) = p.u;
    }
  }
}

// ---------------- S: bidirectional GRU scan — rd16 (proven best: 548us) ----------------
// grid = 128 blocks x 128 threads: dir = bx>>6, m = (bx>>4)&3 (batch tile of 16 rows),
// n = bx&15 (feature slice of 32, 2 waves x 16). Group (dir,m) = 16 producers syncing
// only among themselves; 8 groups drift independently. Per wave: 48 Wh B-fragments
// pinned in regs (loaded once from global; asm opacity blocks rematerialization).
// Per-step: hot-poll 16 flags -> 32 relaxed agent 8B h-loads -> 48 MFMA -> gates ->
// per-wave 16x16 LDS transpose (wave-local lgkmcnt) -> 8B agent publishes -> 2-wave
// __syncthreads (every wave drains vmcnt(0): publishes acked at coherent point) ->
// per-block flag on its own 64B line. All sync at agent scope (the only protocol
// that has ever worked on this chip — XCD-local variants deadlock, rd20/21).
__global__ __launch_bounds__(128, 1) void k_scan(const f16* __restrict__ xw2, const f16* __restrict__ WhT,
                                                 f16* __restrict__ hbuf, const float* __restrict__ mask,
                                                 float* __restrict__ out, unsigned* __restrict__ flags){
  const int dir = blockIdx.x >> 6;
  const int m   = (blockIdx.x >> 4) & 3;
  const int n   = blockIdx.x & 15;
  const int gidx = dir*4 + m;                 // sync group (8 total)
  __shared__ __align__(16) f16 sX[2*16*16];   // 1KB: per-wave 16x16 transpose scratch
  const int tid = threadIdx.x, l = tid & 63, wv = tid >> 6;   // wv in {0,1}
  const int fl = l & 15, sg = l >> 4;
  const int fbase = n*32 + wv*16;             // this wave's 16 features (within 512)
  // one-time: 48 B-fragments (Wh cols for z,r,h of our features) direct from global, pinned
  f16x8 pz[16], pr[16], ph[16];
  {
    const f16* wb = WhT + (size_t)dir*G3*512;
    #pragma unroll
    for (int kk=0;kk<16;kk++){
      int ko = kk*32 + sg*8;
      pz[kk] = *(const f16x8*)(wb + (size_t)(       fbase + fl)*512 + ko);
      pr[kk] = *(const f16x8*)(wb + (size_t)( 512 + fbase + fl)*512 + ko);
      ph[kk] = *(const f16x8*)(wb + (size_t)(1024 + fbase + fl)*512 + ko);
    }
  }
  #pragma unroll
  for (int kk=0;kk<16;kk++){
    asm volatile("" : "+v"(pz[kk]));
    asm volatile("" : "+v"(pr[kk]));
    asm volatile("" : "+v"(ph[kk]));
  }
  float hstate[4] = {0.f,0.f,0.f,0.f};
  float* out2 = out + (size_t)L_*B_*1024;
  const int mb = m*16 + sg*4;                 // absolute batch base of this lane's C rows
  unsigned* myflag = flags + (size_t)(n*8 + gidx)*16;                  // 64B-strided
  const unsigned* pollp = flags + (size_t)((l&15)*8 + gidx)*16;        // 16 group flags
  f16* const sXw = &sX[wv*256];               // this wave's 512B transpose tile
  const int prow = l >> 2, pf = (l & 3)*4;    // publish mapping after transpose

  for (int ti=0; ti<128; ++ti){
    const int t = dir ? (127 - ti) : ti;
    // ---- prefetch xw gates + mask (independent of h; hides under poll) ----
    size_t xb = ((size_t)t*NCOL + dir*G3 + fbase + fl)*B_ + mb;
    union { uint2 u; f16 h[4]; } xzv, xrv, xhv;
    xzv.u = *(const uint2*)(xw2 + xb);
    xrv.u = *(const uint2*)(xw2 + xb + (size_t)512*B_);
    xhv.u = *(const uint2*)(xw2 + xb + (size_t)1024*B_);
    float4 mv4 = *(const float4*)(mask + t*B_ + mb);
    // ---- wait for previous step's h (this group only), then hw = h @ Wh ----
    f32x4 az = {0,0,0,0}, ar = {0,0,0,0}, ah = {0,0,0,0};
    if (ti){
      unsigned tgt = (unsigned)ti;
      while (true){
        unsigned f = __hip_atomic_load(pollp, __ATOMIC_RELAXED, __HIP_MEMORY_SCOPE_AGENT);
        if (__all((int)(f >= tgt))) break;
      }
      // group h buffer: 16 rows x 512 f16; A-row = batch-within-tile = fl; row = 128 u64
      const u64* hq = (const u64*)(hbuf + ((size_t)gidx*2 + (ti&1))*(16*512)) + (size_t)fl*128;
      u64 q[32];
      #pragma unroll
      for (int kk=0;kk<16;kk++){
        int j = kk*8 + sg*2;                // == (kk*4+sg)*2
        q[2*kk  ] = __hip_atomic_load(hq + j,     __ATOMIC_RELAXED, __HIP_MEMORY_SCOPE_AGENT);
        q[2*kk+1] = __hip_atomic_load(hq + j + 1, __ATOMIC_RELAXED, __HIP_MEMORY_SCOPE_AGENT);
      }
      #pragma unroll
      for (int kk=0;kk<16;kk++){
        union { u64 d[2]; f16x8 h; } a;
        a.d[0] = q[2*kk]; a.d[1] = q[2*kk+1];
        az = __builtin_amdgcn_mfma_f32_16x16x32_f16(a.h, pz[kk], az, 0,0,0);
        ar = __builtin_amdgcn_mfma_f32_16x16x32_f16(a.h, pr[kk], ar, 0,0,0);
        ah = __builtin_amdgcn_mfma_f32_16x16x32_f16(a.h, ph[kk], ah, 0,0,0);
      }
    }
    // ---- gates + state update (lane = feature fbase+fl, batch rows mb..mb+3) ----
    #pragma unroll
    for (int r=0;r<4;r++){
      float z  = sigm_((float)xzv.h[r] + az[r]);
      float rr = sigm_((float)xrv.h[r] + ar[r]);
      float ht = tanh_((float)xhv.h[r] + rr*ah[r]);
      float mv = (&mv4.x)[r];
      float hn = (1.0f - z)*hstate[r] + z*ht;
      hn = mv*hn + (1.0f - mv)*hstate[r];
      hstate[r] = hn;
    }
    // ---- publish: per-wave LDS transpose -> 8B stores -> barrier -> block flag ----
    if (ti < 127){
      #pragma unroll
      for (int r=0;r<4;r++) sXw[(sg*4 + r)*16 + fl] = (f16)hstate[r];
      asm volatile("s_waitcnt lgkmcnt(0)" ::: "memory");   // wave-local ds ordering
      u64 v = *(const u64*)&sXw[prow*16 + pf];
      f16* hb = hbuf + ((size_t)gidx*2 + ((ti&1)^1))*(16*512);
      __hip_atomic_store((u64*)(hb + (size_t)prow*512 + n*32 + wv*16 + pf), v,
                         __ATOMIC_RELAXED, __HIP_MEMORY_SCOPE_AGENT);
      __syncthreads();            // both waves drain vmcnt(0): publishes acked
      if (tid == 0)
        __hip_atomic_store(myflag, (unsigned)(ti+1),
                           __ATOMIC_RELAXED, __HIP_MEMORY_SCOPE_AGENT);
    }
    // ---- outputs (after the flag, off the critical path) ----
    #pragma unroll
    for (int r=0;r<4;r++)
      out[((size_t)(t*B_ + mb + r))*1024 + dir*512 + fbase + fl] = hstate[r];
    if (dir==1 && t==0){
      #pragma unroll
      for (int r=0;r<4;r++)
        out2[(size_t)(mb + r)*512 + fbase + fl] = hstate[r];
    }
  }
}

extern "C" void kernel_launch(void* const* d_in, const int* in_sizes, int n_in,
                              void* d_out, int out_size, void* d_ws, size_t ws_size,
                              hipStream_t stream){
  const int*   xs      = (const int*)  d_in[0];
  const float* xs_mask = (const float*)d_in[1];
  const float* emb     = (const float*)d_in[2];
  const float* Wx_f    = (const float*)d_in[3];
  const float* Wh_f    = (const float*)d_in[4];
  const float* b_f     = (const float*)d_in[5];
  const float* Wx_b    = (const float*)d_in[6];
  const float* Wh_b    = (const float*)d_in[7];
  const float* b_b     = (const float*)d_in[8];

  char* w = (char*)d_ws;
  f16*      Xe    = (f16*)(w);                  //  8,388,608 B
  f16*      WxT   = (f16*)(w + 8388608);        //  3,145,728 B
  f16*      WhT   = (f16*)(w + 11534336);       //  3,145,728 B
  f16*      xw2   = (f16*)(w + 14680064);       // 50,331,648 B
  f16*      hbuf  = (f16*)(w + 65011712);       //    262,144 B (8 groups x 2 x 16KB)
  unsigned* flags = (unsigned*)(w + 65273856);  //      8,192 B (128 flags x 64B)
  float*    out   = (float*)d_out;

  k_embed    <<<dim3(4096),    dim3(256), 0, stream>>>(xs, emb, Xe, (uint4*)flags);
  k_transpose<<<dim3(24,8,4),  dim3(256), 0, stream>>>(Wx_f, Wx_b, Wh_f, Wh_b, WxT, WhT);
  k_gemm     <<<dim3(24,64),   dim3(256), 0, stream>>>(Xe, WxT, b_f, b_b, xw2);
  k_scan     <<<dim3(128),     dim3(128), 0, stream>>>(xw2, WhT, hbuf, xs_mask, out, flags);
}